// Round 11
// baseline (845.794 us; speedup 1.0000x reference)
//
#include <hip/hip_runtime.h>

// z <- tanh(z @ W^T + x), 50 fixed-point steps. B=16384, D=512.
// Round 11: round-10 geometry (TM=64, ONE 1024-thread block/CU, 16 waves =
// 4/SIMD, Occupancy 44.7 verified) + REGISTER-RESIDENT HALF W-SLAB.
// Round-10 counters: VGPR 56, iter 9.4 us of which W L2 stream (512 KB/CU-
// iter / ~135 GB/s per-CU L2 share) ~ 3.8 us is the largest component.
// Each wave hoists ks=0..15 A-fragments (ra[16] = 64 VGPRs, iteration-
// invariant, fully-unrolled compile-time indexing) -> W L2 traffic halves.
// Feasible now (56+64 ~ 120 < 128 cap) where rounds 1-3 spilled (needed 230).
// Known-kept: double-buffered z (2 x 64 KB), ONE barrier/iter; x in 16
// packed-fp16 VGPRs (per-iter global x reads thrash L2, rounds 5/6);
// W pre-scaled by K = 2*log2(e) as bf16 MFMA A-fragments in d_ws;
// tanh = 1 - 2/(exp2(s)+1), no clamp (|s| < 128 always, round-8 verified);
// pack via v_cvt_pk_bf16_f32. B ds_reads are 4-way-conflict-bound (b128 has
// only 8 granule positions; 5.8e7 counter) -- next round's target.

typedef short s8v  __attribute__((ext_vector_type(8)));   // 8 bf16 = 4 VGPRs
typedef float f32x16 __attribute__((ext_vector_type(16)));
typedef _Float16 h4 __attribute__((ext_vector_type(4)));  // 4 fp16 = 2 VGPRs

#define BATCH 16384
#define DIM   512
#define TM    64        // rows per block
#define NITER 50        // 1 init step + 49 GEMM steps
#define NH    16        // hoisted A-fragments per wave (64 VGPRs)

#define KSC 2.8853900817779268f    // 2*log2(e)

__device__ __forceinline__ unsigned short f2bf(float f) {
    unsigned int u = __float_as_uint(f);
    u += 0x7fffu + ((u >> 16) & 1u);          // round-to-nearest-even
    return (unsigned short)(u >> 16);
}

// W (fp32 [512][512] row-major) -> K-prescaled bf16 A-fragments for
// v_mfma_f32_32x32x16_bf16. Granule tid = (jt*32 + ks)*64 + lane holds
// K*W[j = 32*jt + (lane&31)][k = 16*ks + 8*(lane>>5) .. +8] as 16 B.
__global__ void wprep_kernel(const float* __restrict__ W, unsigned short* __restrict__ Wf) {
    int tid = blockIdx.x * blockDim.x + threadIdx.x;   // 0..32767
    int jt  = tid >> 11;
    int rem = tid & 2047;
    int ks  = rem >> 6;
    int L   = rem & 63;
    int j   = jt * 32 + (L & 31);
    int k   = ks * 16 + (L >> 5) * 8;
    const float* src = W + j * DIM + k;
    uint4 p;
    p.x = (unsigned)f2bf(src[0] * KSC) | ((unsigned)f2bf(src[1] * KSC) << 16);
    p.y = (unsigned)f2bf(src[2] * KSC) | ((unsigned)f2bf(src[3] * KSC) << 16);
    p.z = (unsigned)f2bf(src[4] * KSC) | ((unsigned)f2bf(src[5] * KSC) << 16);
    p.w = (unsigned)f2bf(src[6] * KSC) | ((unsigned)f2bf(src[7] * KSC) << 16);
    ((uint4*)Wf)[tid] = p;
}

// LDS z layout: row r x 512 bf16, 64 chunks of 16 B per row, XOR swizzle
// chunk' = chunk ^ (r & 7) -> spreads bank groups for ds_read_b128 / writes.
__device__ __forceinline__ int z_addr(int r, int j) {   // element index
    int c  = j >> 3;
    int lo = j & 7;
    return r * DIM + (((c ^ (r & 7)) << 3) | lo);
}

__device__ __forceinline__ unsigned pk_bf16(float lo, float hi) {
    unsigned r;
    asm("v_cvt_pk_bf16_f32 %0, %1, %2" : "=v"(r) : "v"(lo), "v"(hi));  // RNE
    return r;
}

// s is the ALREADY K-SCALED argument: tanh(v) where s = K*v. No clamp:
// reachable |s| < 128, exp2 finite (or rcp limit gives exactly +-1).
__device__ __forceinline__ float tanh_pre(float s) {
    float t = __builtin_amdgcn_exp2f(s);
    float q = __builtin_amdgcn_rcpf(t + 1.0f);
    return fmaf(-2.0f, q, 1.0f);            // (t-1)/(t+1) == 1 - 2/(t+1)
}

__device__ __forceinline__ f32x16 zero16() {
    f32x16 v;
#pragma unroll
    for (int i = 0; i < 16; ++i) v[i] = 0.0f;
    return v;
}

__device__ __forceinline__ h4 cvt_h4(float4 t) {
    h4 r;
    r[0] = (_Float16)t.x; r[1] = (_Float16)t.y;
    r[2] = (_Float16)t.z; r[3] = (_Float16)t.w;
    return r;
}

__global__ __launch_bounds__(1024, 4)
void fixpoint_kernel(const float* __restrict__ x,
                     const unsigned short* __restrict__ Wf,
                     float* __restrict__ out) {
    __shared__ alignas(16) unsigned short zt[2][TM * DIM];   // 128 KB double buffer

    const int tid  = threadIdx.x;
    const int lane = tid & 63;
    const int w    = tid >> 6;       // wave 0..15, owns j-slab [32w, 32w+32)
    const int l31  = lane & 31;
    const int h    = lane >> 5;      // k-half for A/B fragments
    const int r0   = blockIdx.x * TM;
    const int jb0  = 32 * w;
    const int swz  = l31 & 7;        // z-row swizzle key

    const s8v* Wfv = (const s8v*)Wf;

    // ---- x -> 16 packed-fp16 VGPRs, fragment order (the ONLY global x read) ----
    // xa[g]: row l31, cols jb0+8g+4h.. ; xb[g]: row l31+32, same cols.
    h4 xa[4], xb[4];
    {
        const float* xr0 = x + (size_t)(r0 + l31) * DIM;
        const float* xr1 = x + (size_t)(r0 + l31 + 32) * DIM;
#pragma unroll
        for (int g = 0; g < 4; ++g) {
            const int j0 = jb0 + 8 * g + 4 * h;
            xa[g] = cvt_h4(*(const float4*)&xr0[j0]);
            xb[g] = cvt_h4(*(const float4*)&xr1[j0]);
        }
    }

    // ---- resident A: ks = 0..NH-1 (iteration-invariant, 4*NH VGPRs) ----
    s8v ra[NH];
#pragma unroll
    for (int ks = 0; ks < NH; ++ks)
        ra[ks] = Wfv[(w * 32 + ks) * 64 + lane];

    f32x16 ac0, ac1;   // rows l31-block / l31+32-block of the 32j x 64r tile

    // acc layout: col = lane&31 -> z-row; row = (reg&3)+8*(reg>>2)+4h -> j
    auto epi_z = [&](unsigned short* __restrict__ zn) {
#pragma unroll
        for (int g = 0; g < 4; ++g) {
            const int j0 = jb0 + 8 * g + 4 * h;
            uint2 p;
            p.x = pk_bf16(tanh_pre(fmaf((float)xa[g][0], KSC, ac0[4*g+0])),
                          tanh_pre(fmaf((float)xa[g][1], KSC, ac0[4*g+1])));
            p.y = pk_bf16(tanh_pre(fmaf((float)xa[g][2], KSC, ac0[4*g+2])),
                          tanh_pre(fmaf((float)xa[g][3], KSC, ac0[4*g+3])));
            *(uint2*)&zn[z_addr(l31, j0)] = p;
            p.x = pk_bf16(tanh_pre(fmaf((float)xb[g][0], KSC, ac1[4*g+0])),
                          tanh_pre(fmaf((float)xb[g][1], KSC, ac1[4*g+1])));
            p.y = pk_bf16(tanh_pre(fmaf((float)xb[g][2], KSC, ac1[4*g+2])),
                          tanh_pre(fmaf((float)xb[g][3], KSC, ac1[4*g+3])));
            *(uint2*)&zn[z_addr(l31 + 32, j0)] = p;
        }
    };

    auto epi_out = [&]() {
        float* o0 = out + (size_t)(r0 + l31) * DIM;
        float* o1 = out + (size_t)(r0 + l31 + 32) * DIM;
#pragma unroll
        for (int g = 0; g < 4; ++g) {
            const int j0 = jb0 + 8 * g + 4 * h;
            float4 v;
            v.x = tanh_pre(fmaf((float)xa[g][0], KSC, ac0[4*g+0]));
            v.y = tanh_pre(fmaf((float)xa[g][1], KSC, ac0[4*g+1]));
            v.z = tanh_pre(fmaf((float)xa[g][2], KSC, ac0[4*g+2]));
            v.w = tanh_pre(fmaf((float)xa[g][3], KSC, ac0[4*g+3]));
            *(float4*)&o0[j0] = v;
            v.x = tanh_pre(fmaf((float)xb[g][0], KSC, ac1[4*g+0]));
            v.y = tanh_pre(fmaf((float)xb[g][1], KSC, ac1[4*g+1]));
            v.z = tanh_pre(fmaf((float)xb[g][2], KSC, ac1[4*g+2]));
            v.w = tanh_pre(fmaf((float)xb[g][3], KSC, ac1[4*g+3]));
            *(float4*)&o1[j0] = v;
        }
    };

    auto gemm = [&](const unsigned short* __restrict__ zc) {
        ac0 = zero16(); ac1 = zero16();
        // hoisted half: pure reg A, fully unrolled (compile-time ra index)
#pragma unroll
        for (int ks = 0; ks < NH; ++ks) {
            const int c = ((2 * ks + h) ^ swz) << 3;
            s8v b0 = *(const s8v*)&zc[l31 * DIM + c];
            s8v b1 = *(const s8v*)&zc[(l31 + 32) * DIM + c];
            ac0 = __builtin_amdgcn_mfma_f32_32x32x16_bf16(ra[ks], b0, ac0, 0, 0, 0);
            ac1 = __builtin_amdgcn_mfma_f32_32x32x16_bf16(ra[ks], b1, ac1, 0, 0, 0);
        }
        // streamed half
#pragma unroll 4
        for (int ks = NH; ks < 32; ++ks) {
            s8v a = Wfv[(w * 32 + ks) * 64 + lane];
            const int c = ((2 * ks + h) ^ swz) << 3;
            s8v b0 = *(const s8v*)&zc[l31 * DIM + c];
            s8v b1 = *(const s8v*)&zc[(l31 + 32) * DIM + c];
            ac0 = __builtin_amdgcn_mfma_f32_32x32x16_bf16(a, b0, ac0, 0, 0, 0);
            ac1 = __builtin_amdgcn_mfma_f32_32x32x16_bf16(a, b1, ac1, 0, 0, 0);
        }
    };

    // ---- step 1: z0 = tanh(K*x) via the epi path with zero acc ----
    ac0 = zero16(); ac1 = zero16();
    epi_z(zt[0]);
    __syncthreads();

    int cur = 0;
#pragma unroll 1
    for (int it = 0; it < NITER - 2; ++it) {     // 48 LDS->LDS steps
        gemm(zt[cur]);
        epi_z(zt[cur ^ 1]);   // other buffer: safe vs lagging waves' gemm reads
        __syncthreads();      // single barrier: writes visible, flip together
        cur ^= 1;
    }
    // ---- step 50: fp32 store to out ----
    gemm(zt[cur]);
    epi_out();
}

extern "C" void kernel_launch(void* const* d_in, const int* in_sizes, int n_in,
                              void* d_out, int out_size, void* d_ws, size_t ws_size,
                              hipStream_t stream) {
    const float* x = (const float*)d_in[0];   // [16384, 512] fp32
    const float* W = (const float*)d_in[1];   // [512, 512] fp32
    float* out = (float*)d_out;               // [16384, 512] fp32
    unsigned short* Wf = (unsigned short*)d_ws;   // 512 KB bf16 fragments (K-prescaled)

    wprep_kernel<<<128, 256, 0, stream>>>(W, Wf);
    fixpoint_kernel<<<BATCH / TM, 1024, 0, stream>>>(x, Wf, out);
}

// Round 12
// 489.361 us; speedup vs baseline: 1.7284x; 1.7284x over previous
//
#include <hip/hip_runtime.h>

// z <- tanh(z @ W^T + x), 50 fixed-point steps. B=16384, D=512.
// Round 12: round-10 geometry (TM=64, ONE 1024-thread block/CU, 16 waves =
// 4/SIMD, dbuf z, ONE barrier/iter) + z stored in LDS in MFMA B-FRAGMENT
// ORDER. Round-10's B-reads were 4-way bank-conflicted (5.78e7 cycles:
// row-strided ds_read_b128 with only a 3-bit XOR key). Fragment order makes
// every gemm B-load a wave-contiguous 1024-B ds_read_b128 (conflict-free,
// canonical pattern) with ks folded into the IMMEDIATE offset -> zero per-ks
// address VALU. The 4-way conflict moves to the 16 epi writes only.
//   zfrag[rt][ks][lane] = z[r = 32rt + (lane&31)][k = 16ks + 8(lane>>5)..+8]
//   element index: ((r>>5)<<14) + ((j>>4)<<9) + (((r&31)+32*((j>>3)&1))<<3) + (j&7)
// W streams from L2 (register-resident W abandoned FOR GOOD: 4 geometries,
// 4 spills -- rounds 1,2,3,11; allocator caps arch VGPRs hard).
// x in 16 packed-fp16 VGPRs (per-iter global x reads thrash L2, rounds 5/6).
// W pre-scaled by K = 2*log2(e), bf16 A-fragments in d_ws (L2-resident).
// tanh = 1 - 2/(exp2(s)+1), no clamp (|s| < 128 always; round-8 verified).
// Pack via v_cvt_pk_bf16_f32. Reg budget ~60: acc 32 + x 16 + misc.

typedef short s8v  __attribute__((ext_vector_type(8)));   // 8 bf16 = 4 VGPRs
typedef float f32x16 __attribute__((ext_vector_type(16)));
typedef _Float16 h4 __attribute__((ext_vector_type(4)));  // 4 fp16 = 2 VGPRs

#define BATCH 16384
#define DIM   512
#define TM    64        // rows per block
#define NITER 50        // 1 init step + 49 GEMM steps

#define KSC 2.8853900817779268f    // 2*log2(e)

__device__ __forceinline__ unsigned short f2bf(float f) {
    unsigned int u = __float_as_uint(f);
    u += 0x7fffu + ((u >> 16) & 1u);          // round-to-nearest-even
    return (unsigned short)(u >> 16);
}

// W (fp32 [512][512] row-major) -> K-prescaled bf16 A-fragments for
// v_mfma_f32_32x32x16_bf16. Granule tid = (jt*32 + ks)*64 + lane holds
// K*W[j = 32*jt + (lane&31)][k = 16*ks + 8*(lane>>5) .. +8] as 16 B.
__global__ void wprep_kernel(const float* __restrict__ W, unsigned short* __restrict__ Wf) {
    int tid = blockIdx.x * blockDim.x + threadIdx.x;   // 0..32767
    int jt  = tid >> 11;
    int rem = tid & 2047;
    int ks  = rem >> 6;
    int L   = rem & 63;
    int j   = jt * 32 + (L & 31);
    int k   = ks * 16 + (L >> 5) * 8;
    const float* src = W + j * DIM + k;
    uint4 p;
    p.x = (unsigned)f2bf(src[0] * KSC) | ((unsigned)f2bf(src[1] * KSC) << 16);
    p.y = (unsigned)f2bf(src[2] * KSC) | ((unsigned)f2bf(src[3] * KSC) << 16);
    p.z = (unsigned)f2bf(src[4] * KSC) | ((unsigned)f2bf(src[5] * KSC) << 16);
    p.w = (unsigned)f2bf(src[6] * KSC) | ((unsigned)f2bf(src[7] * KSC) << 16);
    ((uint4*)Wf)[tid] = p;
}

// z element (r, j) -> element index in B-fragment-ordered LDS buffer.
__device__ __forceinline__ int zf_addr(int r, int j) {
    return ((r >> 5) << 14) + ((j >> 4) << 9)
         + (((r & 31) + ((j >> 3) & 1) * 32) << 3) + (j & 7);
}

__device__ __forceinline__ unsigned pk_bf16(float lo, float hi) {
    unsigned r;
    asm("v_cvt_pk_bf16_f32 %0, %1, %2" : "=v"(r) : "v"(lo), "v"(hi));  // RNE
    return r;
}

// s is the ALREADY K-SCALED argument: tanh(v) where s = K*v. No clamp:
// reachable |s| < 128, exp2 finite (or rcp limit gives exactly +-1).
__device__ __forceinline__ float tanh_pre(float s) {
    float t = __builtin_amdgcn_exp2f(s);
    float q = __builtin_amdgcn_rcpf(t + 1.0f);
    return fmaf(-2.0f, q, 1.0f);            // (t-1)/(t+1) == 1 - 2/(t+1)
}

__device__ __forceinline__ f32x16 zero16() {
    f32x16 v;
#pragma unroll
    for (int i = 0; i < 16; ++i) v[i] = 0.0f;
    return v;
}

__device__ __forceinline__ h4 cvt_h4(float4 t) {
    h4 r;
    r[0] = (_Float16)t.x; r[1] = (_Float16)t.y;
    r[2] = (_Float16)t.z; r[3] = (_Float16)t.w;
    return r;
}

__global__ __launch_bounds__(1024, 4)
void fixpoint_kernel(const float* __restrict__ x,
                     const unsigned short* __restrict__ Wf,
                     float* __restrict__ out) {
    __shared__ alignas(16) unsigned short zt[2][TM * DIM];   // 128 KB double buffer

    const int tid  = threadIdx.x;
    const int lane = tid & 63;
    const int w    = tid >> 6;       // wave 0..15, owns j-slab [32w, 32w+32)
    const int l31  = lane & 31;
    const int h    = lane >> 5;      // k-half for A/B fragments
    const int r0   = blockIdx.x * TM;
    const int jb0  = 32 * w;

    const s8v* Wfv = (const s8v*)Wf;

    // ---- x -> 16 packed-fp16 VGPRs, fragment order (the ONLY global x read) ----
    // xa[g]: row l31, cols jb0+8g+4h.. ; xb[g]: row l31+32, same cols.
    h4 xa[4], xb[4];
    {
        const float* xr0 = x + (size_t)(r0 + l31) * DIM;
        const float* xr1 = x + (size_t)(r0 + l31 + 32) * DIM;
#pragma unroll
        for (int g = 0; g < 4; ++g) {
            const int j0 = jb0 + 8 * g + 4 * h;
            xa[g] = cvt_h4(*(const float4*)&xr0[j0]);
            xb[g] = cvt_h4(*(const float4*)&xr1[j0]);
        }
    }

    // Iteration-invariant A fragments for ks=0,1 (gemm starts without L2 wait)
    const s8v a_h0 = Wfv[(w * 32 + 0) * 64 + lane];
    const s8v a_h1 = Wfv[(w * 32 + 1) * 64 + lane];

    f32x16 ac0, ac1;   // rows l31 / l31+32 of the 32j x 64r tile

    // acc layout: col = lane&31 -> z-row; row = (reg&3)+8*(reg>>2)+4h -> j
    auto epi_z = [&](unsigned short* __restrict__ zn) {
#pragma unroll
        for (int g = 0; g < 4; ++g) {
            const int j0 = jb0 + 8 * g + 4 * h;
            uint2 p;
            p.x = pk_bf16(tanh_pre(fmaf((float)xa[g][0], KSC, ac0[4*g+0])),
                          tanh_pre(fmaf((float)xa[g][1], KSC, ac0[4*g+1])));
            p.y = pk_bf16(tanh_pre(fmaf((float)xa[g][2], KSC, ac0[4*g+2])),
                          tanh_pre(fmaf((float)xa[g][3], KSC, ac0[4*g+3])));
            *(uint2*)&zn[zf_addr(l31, j0)] = p;        // 8 B, (j0&7)in{0,4} aligned
            p.x = pk_bf16(tanh_pre(fmaf((float)xb[g][0], KSC, ac1[4*g+0])),
                          tanh_pre(fmaf((float)xb[g][1], KSC, ac1[4*g+1])));
            p.y = pk_bf16(tanh_pre(fmaf((float)xb[g][2], KSC, ac1[4*g+2])),
                          tanh_pre(fmaf((float)xb[g][3], KSC, ac1[4*g+3])));
            *(uint2*)&zn[zf_addr(l31 + 32, j0)] = p;
        }
    };

    auto epi_out = [&]() {
        float* o0 = out + (size_t)(r0 + l31) * DIM;
        float* o1 = out + (size_t)(r0 + l31 + 32) * DIM;
#pragma unroll
        for (int g = 0; g < 4; ++g) {
            const int j0 = jb0 + 8 * g + 4 * h;
            float4 v;
            v.x = tanh_pre(fmaf((float)xa[g][0], KSC, ac0[4*g+0]));
            v.y = tanh_pre(fmaf((float)xa[g][1], KSC, ac0[4*g+1]));
            v.z = tanh_pre(fmaf((float)xa[g][2], KSC, ac0[4*g+2]));
            v.w = tanh_pre(fmaf((float)xa[g][3], KSC, ac0[4*g+3]));
            *(float4*)&o0[j0] = v;
            v.x = tanh_pre(fmaf((float)xb[g][0], KSC, ac1[4*g+0]));
            v.y = tanh_pre(fmaf((float)xb[g][1], KSC, ac1[4*g+1]));
            v.z = tanh_pre(fmaf((float)xb[g][2], KSC, ac1[4*g+2]));
            v.w = tanh_pre(fmaf((float)xb[g][3], KSC, ac1[4*g+3]));
            *(float4*)&o1[j0] = v;
        }
    };

    // gemm: B-fragment reads are wave-contiguous (base = lane*16 B) with
    // ks in the immediate offset: b0 at granule ks*64+lane, b1 at +32*64.
    auto gemm = [&](const unsigned short* __restrict__ zc) {
        const s8v* zb = (const s8v*)zc + lane;     // granule pointer, lane base
        ac0 = zero16(); ac1 = zero16();
        {   // ks = 0, 1 with hoisted A
            s8v b0 = zb[0];
            s8v b1 = zb[32 * 64];
            ac0 = __builtin_amdgcn_mfma_f32_32x32x16_bf16(a_h0, b0, ac0, 0, 0, 0);
            ac1 = __builtin_amdgcn_mfma_f32_32x32x16_bf16(a_h0, b1, ac1, 0, 0, 0);
            b0 = zb[64];
            b1 = zb[33 * 64];
            ac0 = __builtin_amdgcn_mfma_f32_32x32x16_bf16(a_h1, b0, ac0, 0, 0, 0);
            ac1 = __builtin_amdgcn_mfma_f32_32x32x16_bf16(a_h1, b1, ac1, 0, 0, 0);
        }
#pragma unroll 6
        for (int ks = 2; ks < 32; ++ks) {
            s8v a = Wfv[(w * 32 + ks) * 64 + lane];
            s8v b0 = zb[ks * 64];
            s8v b1 = zb[(32 + ks) * 64];
            ac0 = __builtin_amdgcn_mfma_f32_32x32x16_bf16(a, b0, ac0, 0, 0, 0);
            ac1 = __builtin_amdgcn_mfma_f32_32x32x16_bf16(a, b1, ac1, 0, 0, 0);
        }
    };

    // ---- step 1: z0 = tanh(K*x) via the epi path with zero acc ----
    ac0 = zero16(); ac1 = zero16();
    epi_z(zt[0]);
    __syncthreads();

    int cur = 0;
#pragma unroll 1
    for (int it = 0; it < NITER - 2; ++it) {     // 48 LDS->LDS steps
        gemm(zt[cur]);
        epi_z(zt[cur ^ 1]);   // other buffer: safe vs lagging waves' gemm reads
        __syncthreads();      // single barrier: writes visible, flip together
        cur ^= 1;
    }
    // ---- step 50: fp32 store to out ----
    gemm(zt[cur]);
    epi_out();
}

extern "C" void kernel_launch(void* const* d_in, const int* in_sizes, int n_in,
                              void* d_out, int out_size, void* d_ws, size_t ws_size,
                              hipStream_t stream) {
    const float* x = (const float*)d_in[0];   // [16384, 512] fp32
    const float* W = (const float*)d_in[1];   // [512, 512] fp32
    float* out = (float*)d_out;               // [16384, 512] fp32
    unsigned short* Wf = (unsigned short*)d_ws;   // 512 KB bf16 fragments (K-prescaled)

    wprep_kernel<<<128, 256, 0, stream>>>(W, Wf);
    fixpoint_kernel<<<BATCH / TM, 1024, 0, stream>>>(x, Wf, out);
}